// Round 2
// baseline (1892.961 us; speedup 1.0000x reference)
//
#include <hip/hip_runtime.h>
#include <hip/hip_bf16.h>
#include <type_traits>

#define DD    512
#define HH    8
#define HD    64
#define NLAYER 6
#define DFFN  2048
#define LATD  256
#define BB    4
#define LQQ   512
#define LCC   128

typedef unsigned short u16;
typedef __attribute__((ext_vector_type(8))) short bf16x8;
typedef __attribute__((ext_vector_type(4))) float f32x4;
typedef __attribute__((ext_vector_type(4))) unsigned short u16x4;

__device__ __forceinline__ u16 f2bf(float f) {
    __hip_bfloat16 h = __float2bfloat16(f);
    return __builtin_bit_cast(u16, h);
}
__device__ __forceinline__ float bf2f(u16 u) {
    return __uint_as_float(((unsigned int)u) << 16);
}
// load 8 consecutive fp32, convert to 8 bf16 packed in a uint4 (LDS image)
__device__ __forceinline__ uint4 ld8_cvt(const float* p) {
    const float4 a = *(const float4*)p;
    const float4 b = *(const float4*)(p + 4);
    uint4 r;
    r.x = (unsigned)f2bf(a.x) | ((unsigned)f2bf(a.y) << 16);
    r.y = (unsigned)f2bf(a.z) | ((unsigned)f2bf(a.w) << 16);
    r.z = (unsigned)f2bf(b.x) | ((unsigned)f2bf(b.y) << 16);
    r.w = (unsigned)f2bf(b.z) | ((unsigned)f2bf(b.w) << 16);
    return r;
}

// ---------------------------------------------------------------------------
// MFMA bf16 GEMM. B is [N][K] row-major. A/B may be fp32 in HBM (AF32/BF32):
// converted to bf16 inline during register staging (identical f2bf rounding,
// kills the separate weight-conversion pass).
// BK=64, LDS double-buffer + 2-slot register pipeline.
// MULTI: blockIdx.z selects (B,C) from up to 3; else z=zb*Hdim+zh batches.
// wt: transposed epilogue C[gn*ldct + (gm>>wt_shift)*sbT + (gm&mask)].
// normal: v=alpha*acc + bias[n]; act==1 exact gelu; += res[(gm>>rs)*ldres+gn].
// ---------------------------------------------------------------------------
template<int BM, int BN, typename TC, bool MULTI, bool BF32 = false, bool AF32 = false>
__global__ __launch_bounds__(256)
void k_g(const void* __restrict__ A, long long sAb, long long sAh, int lda,
         const void* __restrict__ B1, const void* __restrict__ B2_, const void* __restrict__ B3_,
         long long sBb, long long sBh, int ldb,
         TC* __restrict__ C1, TC* __restrict__ C2_, TC* __restrict__ C3_,
         long long sCb, long long sCh, int ldc,
         int K, int Hdim, float alpha,
         const float* __restrict__ bias,
         const float* __restrict__ res, int ldres, int res_shift,
         float beta2, const u16* __restrict__ add2, long long s2b, long long s2h,
         int act, int wt_mask, int wt_shift, long long sbT, int ldct)
{
    constexpr int SK = 72;
    constexpr int FM = BM / 32, FN = BN / 32;
    constexpr int PA = BM / 32, PB = BN / 32;
    constexpr int EA = AF32 ? 4 : 2, EB = BF32 ? 4 : 2;

    const int z = blockIdx.z;
    const char* Ab = (const char*)A;
    const char* Bb;
    TC* C;
    int wt;
    if constexpr (MULTI) {
        Bb = (const char*)((z == 0) ? B1 : ((z == 1) ? B2_ : B3_));
        C  = (z == 0) ? C1 : ((z == 1) ? C2_ : C3_);
        wt = (wt_mask >> z) & 1;
    } else {
        const int zb = z / Hdim, zh = z % Hdim;
        Ab += (size_t)(zb * sAb + zh * sAh) * EA;
        Bb = (const char*)B1 + (size_t)(zb * sBb + zh * sBh) * EB;
        C  = C1 + (size_t)(zb * sCb + zh * sCh);
        if (add2) add2 += (size_t)(zb * s2b + zh * s2h);
        wt = wt_mask & 1;
    }

    __shared__ u16 Asm[2][BM * SK];
    __shared__ u16 Bsm[2][BN * SK];

    const int t    = threadIdx.x;
    const int wid  = t >> 6, lane = t & 63;
    const int q    = lane >> 4, c = lane & 15;
    const int wm   = (wid >> 1) * (BM / 2), wn = (wid & 1) * (BN / 2);
    const int m0   = blockIdx.y * BM, n0 = blockIdx.x * BN;

    f32x4 acc[FM][FN];
    #pragma unroll
    for (int i = 0; i < FM; i++)
        #pragma unroll
        for (int j = 0; j < FN; j++) acc[i][j] = (f32x4){0.f, 0.f, 0.f, 0.f};

    uint4 ra[2][PA], rb[2][PB];
    const int NI = K >> 6;

    auto loadg = [&](int slot, int kt) {
        #pragma unroll
        for (int p = 0; p < PA; p++) {
            const int idx = p * 256 + t, r = idx >> 3, kg = (idx & 7) << 3;
            if constexpr (AF32)
                ra[slot][p] = ld8_cvt((const float*)Ab + (size_t)(m0 + r) * lda + kt + kg);
            else
                ra[slot][p] = *(const uint4*)((const u16*)Ab + (size_t)(m0 + r) * lda + kt + kg);
        }
        #pragma unroll
        for (int p = 0; p < PB; p++) {
            const int idx = p * 256 + t, r = idx >> 3, kg = (idx & 7) << 3;
            if constexpr (BF32)
                rb[slot][p] = ld8_cvt((const float*)Bb + (size_t)(n0 + r) * ldb + kt + kg);
            else
                rb[slot][p] = *(const uint4*)((const u16*)Bb + (size_t)(n0 + r) * ldb + kt + kg);
        }
    };
    auto store = [&](int buf, int slot) {
        #pragma unroll
        for (int p = 0; p < PA; p++) {
            const int idx = p * 256 + t, r = idx >> 3, kg = (idx & 7) << 3;
            *(uint4*)&Asm[buf][r * SK + kg] = ra[slot][p];
        }
        #pragma unroll
        for (int p = 0; p < PB; p++) {
            const int idx = p * 256 + t, r = idx >> 3, kg = (idx & 7) << 3;
            *(uint4*)&Bsm[buf][r * SK + kg] = rb[slot][p];
        }
    };

    loadg(0, 0);
    if (NI > 1) loadg(1, 64);
    store(0, 0);

    for (int it = 0; it < NI; it++) {
        __syncthreads();
        const int cur = it & 1, nxt = cur ^ 1;
        if (it + 1 < NI) store(nxt, nxt);
        if (it + 2 < NI) loadg(cur, (it + 2) << 6);
        #pragma unroll
        for (int s = 0; s < 2; s++) {
            bf16x8 af[FM], bfv[FN];
            #pragma unroll
            for (int fm = 0; fm < FM; fm++)
                af[fm] = *(const bf16x8*)&Asm[cur][(wm + fm * 16 + c) * SK + s * 32 + q * 8];
            #pragma unroll
            for (int fn = 0; fn < FN; fn++)
                bfv[fn] = *(const bf16x8*)&Bsm[cur][(wn + fn * 16 + c) * SK + s * 32 + q * 8];
            #pragma unroll
            for (int fm = 0; fm < FM; fm++)
                #pragma unroll
                for (int fn = 0; fn < FN; fn++)
                    acc[fm][fn] = __builtin_amdgcn_mfma_f32_16x16x32_bf16(
                        af[fm], bfv[fn], acc[fm][fn], 0, 0, 0);
        }
    }

    if (wt) {
        if constexpr (std::is_same<TC, u16>::value) {
            #pragma unroll
            for (int fm = 0; fm < FM; fm++) {
                const int gm0 = m0 + wm + fm * 16 + q * 4;
                const long long roff =
                    (long long)(gm0 >> wt_shift) * sbT + (gm0 & ((1 << wt_shift) - 1));
                #pragma unroll
                for (int fn = 0; fn < FN; fn++) {
                    const int gn = n0 + wn + fn * 16 + c;
                    const long long a0 = (long long)gn * ldct + roff;
                    u16x4 o;
                    if (add2) {
                        const u16x4 av = *(const u16x4*)&add2[a0];
                        #pragma unroll
                        for (int r = 0; r < 4; r++)
                            o[r] = f2bf(alpha * acc[fm][fn][r] + beta2 * bf2f(av[r]));
                    } else {
                        #pragma unroll
                        for (int r = 0; r < 4; r++)
                            o[r] = f2bf(alpha * acc[fm][fn][r]);
                    }
                    *(u16x4*)&C[a0] = o;
                }
            }
        }
    } else {
        #pragma unroll
        for (int fm = 0; fm < FM; fm++) {
            #pragma unroll
            for (int reg = 0; reg < 4; reg++) {
                const int gm = m0 + wm + fm * 16 + q * 4 + reg;
                #pragma unroll
                for (int fn = 0; fn < FN; fn++) {
                    const int gn = n0 + wn + fn * 16 + c;
                    float v = alpha * acc[fm][fn][reg];
                    if (bias) v += bias[gn];
                    if (act == 1) v = 0.5f * v * (1.0f + erff(v * 0.7071067811865475f));
                    if (res)  v += res[(size_t)(gm >> res_shift) * ldres + gn];
                    if constexpr (std::is_same<TC, u16>::value)
                        C[(size_t)gm * ldc + gn] = f2bf(v);
                    else
                        C[(size_t)gm * ldc + gn] = v;
                }
            }
        }
    }
}

// ---------------------------------------------------------------------------
// Fused attention: one block = 64 q-rows x one (b,h) head.
// MODE 0 (cross) : LK=128, key mask, epilogue writes ob rows [B*LQ, DD].
// MODE 1 (self A): LK=512, u = P@v, epilogue wT[b,h,64,512] = (0.5u+0.5v)^T.
// MODE 2 (self B): LK=512, RECOMPUTES S+softmax (bit-identical to MODE 1),
//                  then ob = P @ wT (vT arg = wT buffer), row-major epilogue.
// ---------------------------------------------------------------------------
template<int MODE>
__global__ __launch_bounds__(256)
void k_attn(const u16* __restrict__ qb, const u16* __restrict__ kb,
            const u16* __restrict__ vT, u16* __restrict__ uout,
            const float* __restrict__ mask, float alpha)
{
    constexpr bool CROSS = (MODE == 0);
    constexpr int LK  = CROSS ? LCC : LQQ;
    constexpr int NCT = LK / 128;
    constexpr int NJ  = LK / 16;
    constexpr int SM1 = 64 * 72 * 2 + (CROSS ? 1 : 2) * 128 * 72 * 2;
    constexpr int SM2 = 2 * 64 * 136 * 2;
    constexpr int SMEM = SM1 > SM2 ? SM1 : SM2;
    __shared__ char smem[SMEM];
    u16* Qs = (u16*)smem;
    u16* Ks = (u16*)(smem + 64 * 72 * 2);
    u16* Ps = (u16*)smem;
    u16* Vs = (u16*)(smem + 64 * 136 * 2);

    const int z = blockIdx.z, b = z >> 3, hh = z & 7;
    const int m0 = blockIdx.y * 64;
    const int t = threadIdx.x, w = t >> 6, lane = t & 63;
    const int q = lane >> 4, c = lane & 15;

    const u16* qbase = qb + ((size_t)(b * LQQ + m0)) * DD + hh * HD;
    const u16* kbase = kb + ((size_t)b * LK) * DD + hh * HD;
    const u16* vbase = vT + (size_t)z * HD * LK;

    // ---- stage Q (64 x 64) ----
    #pragma unroll
    for (int p = 0; p < 2; p++) {
        const int idx = p * 256 + t, r = idx >> 3, kg = (idx & 7) << 3;
        *(uint4*)&Qs[r * 72 + kg] = *(const uint4*)(qbase + (size_t)r * DD + kg);
    }

    f32x4 acc[NJ];
    #pragma unroll
    for (int j = 0; j < NJ; j++) acc[j] = (f32x4){0.f, 0.f, 0.f, 0.f};

    auto stageK = [&](u16* dst, int ct) {
        #pragma unroll
        for (int p = 0; p < 4; p++) {
            const int idx = p * 256 + t, r = idx >> 3, kg = (idx & 7) << 3;
            *(uint4*)&dst[r * 72 + kg] =
                *(const uint4*)(kbase + (size_t)(ct * 128 + r) * DD + kg);
        }
    };

    stageK(Ks, 0);
    __syncthreads();
    #pragma unroll
    for (int ct = 0; ct < NCT; ct++) {
        u16* cur = Ks + (!CROSS ? (ct & 1) * (128 * 72) : 0);
        if (!CROSS && ct + 1 < NCT)
            stageK(Ks + ((ct + 1) & 1) * (128 * 72), ct + 1);
        #pragma unroll
        for (int s = 0; s < 2; s++) {
            const bf16x8 af = *(const bf16x8*)&Qs[(w * 16 + c) * 72 + s * 32 + q * 8];
            #pragma unroll
            for (int fn = 0; fn < 8; fn++) {
                const bf16x8 bv = *(const bf16x8*)&cur[(fn * 16 + c) * 72 + s * 32 + q * 8];
                acc[ct * 8 + fn] = __builtin_amdgcn_mfma_f32_16x16x32_bf16(
                    af, bv, acc[ct * 8 + fn], 0, 0, 0);
            }
        }
        if (!CROSS && ct + 1 < NCT) __syncthreads();
    }

    // ---- row softmax (rows q*4+reg per wave; cols j*16+c) ----
    bool msk[NJ];
    #pragma unroll
    for (int j = 0; j < NJ; j++) {
        msk[j] = false;
        if (CROSS && mask) msk[j] = (mask[b * LCC + j * 16 + c] == 0.0f);
    }
    float mx[4] = {-3.402823466e38f, -3.402823466e38f, -3.402823466e38f, -3.402823466e38f};
    #pragma unroll
    for (int j = 0; j < NJ; j++)
        #pragma unroll
        for (int r = 0; r < 4; r++) {
            float x = alpha * acc[j][r];
            if (msk[j]) x = -3.402823466e38f;
            acc[j][r] = x;
            mx[r] = fmaxf(mx[r], x);
        }
    #pragma unroll
    for (int r = 0; r < 4; r++)
        #pragma unroll
        for (int m = 8; m; m >>= 1) mx[r] = fmaxf(mx[r], __shfl_xor(mx[r], m, 64));
    float sum[4] = {0.f, 0.f, 0.f, 0.f};
    #pragma unroll
    for (int j = 0; j < NJ; j++)
        #pragma unroll
        for (int r = 0; r < 4; r++) {
            const float e = expf(acc[j][r] - mx[r]);
            acc[j][r] = e;
            sum[r] += e;
        }
    #pragma unroll
    for (int r = 0; r < 4; r++)
        #pragma unroll
        for (int m = 8; m; m >>= 1) sum[r] += __shfl_xor(sum[r], m, 64);
    #pragma unroll
    for (int r = 0; r < 4; r++) sum[r] = 1.0f / sum[r];
    #pragma unroll
    for (int j = 0; j < NJ; j++)
        #pragma unroll
        for (int r = 0; r < 4; r++) acc[j][r] *= sum[r];

    // ---- phase 2: u = P @ v (MODE 0/1) or ob = P @ wT (MODE 2) ----
    f32x4 ua[4];
    #pragma unroll
    for (int fn = 0; fn < 4; fn++) ua[fn] = (f32x4){0.f, 0.f, 0.f, 0.f};

    __syncthreads();   // phase boundary: Qs/Ks -> Ps/Vs alias
    #pragma unroll
    for (int ct = 0; ct < NCT; ct++) {
        #pragma unroll
        for (int j = 0; j < 8; j++)
            #pragma unroll
            for (int r = 0; r < 4; r++)
                Ps[(w * 16 + q * 4 + r) * 136 + j * 16 + c] = f2bf(acc[ct * 8 + j][r]);
        #pragma unroll
        for (int p = 0; p < 4; p++) {
            const int idx = p * 256 + t, rr = idx >> 4, kg = (idx & 15) << 3;
            *(uint4*)&Vs[rr * 136 + kg] =
                *(const uint4*)(vbase + (size_t)rr * LK + ct * 128 + kg);
        }
        __syncthreads();
        #pragma unroll
        for (int ks = 0; ks < 4; ks++) {
            const bf16x8 af = *(const bf16x8*)&Ps[(w * 16 + c) * 136 + ks * 32 + q * 8];
            #pragma unroll
            for (int fn = 0; fn < 4; fn++) {
                const bf16x8 bv = *(const bf16x8*)&Vs[(fn * 16 + c) * 136 + ks * 32 + q * 8];
                ua[fn] = __builtin_amdgcn_mfma_f32_16x16x32_bf16(af, bv, ua[fn], 0, 0, 0);
            }
        }
        if (ct + 1 < NCT) __syncthreads();
    }

    // ---- epilogue ----
    if (MODE == 1) {
        #pragma unroll
        for (int fn = 0; fn < 4; fn++) {
            const int col = fn * 16 + c;
            const size_t a0 = ((size_t)z * HD + col) * LQQ + m0 + w * 16 + q * 4;
            const u16x4 vv = *(const u16x4*)&vT[a0];
            u16x4 o;
            #pragma unroll
            for (int r = 0; r < 4; r++)
                o[r] = f2bf(0.5f * ua[fn][r] + 0.5f * bf2f(vv[r]));
            *(u16x4*)&uout[a0] = o;
        }
    } else {
        #pragma unroll
        for (int fn = 0; fn < 4; fn++)
            #pragma unroll
            for (int r = 0; r < 4; r++)
                uout[((size_t)b * LQQ + m0 + w * 16 + q * 4 + r) * DD + hh * HD + fn * 16 + c] =
                    f2bf(ua[fn][r]);
    }
}

// ---------------------------------------------------------------------------
// single remaining fp32->bf16 conversion: cond tokens (A-operand, reused 12x)
__global__ __launch_bounds__(256)
void k_cvt(const float* __restrict__ src, u16* __restrict__ dst, int n4)
{
    const int i4 = blockIdx.x * 256 + threadIdx.x;
    if (i4 >= n4) return;
    const float4 v = *(const float4*)(src + (size_t)i4 * 4);
    u16x4 u = { f2bf(v.x), f2bf(v.y), f2bf(v.z), f2bf(v.w) };
    *(u16x4*)(dst + (size_t)i4 * 4) = u;
}

// ---------------------------------------------------------------------------
__global__ __launch_bounds__(256)
void k_ln(const float* __restrict__ X, u16* __restrict__ Y,
          const float* __restrict__ g, const float* __restrict__ b)
{
    const int row  = blockIdx.x * 4 + threadIdx.y;
    const int lane = threadIdx.x;
    const float* x = X + (size_t)row * DD;
    float v[8];
    float s = 0.0f;
    #pragma unroll
    for (int i = 0; i < 8; i++) { v[i] = x[lane + i * 64]; s += v[i]; }
    #pragma unroll
    for (int off = 32; off; off >>= 1) s += __shfl_xor(s, off, 64);
    const float m = s * (1.0f / 512.0f);
    float qq = 0.0f;
    #pragma unroll
    for (int i = 0; i < 8; i++) { const float d = v[i] - m; qq += d * d; }
    #pragma unroll
    for (int off = 32; off; off >>= 1) qq += __shfl_xor(qq, off, 64);
    const float r = rsqrtf(qq * (1.0f / 512.0f) + 1e-5f);
    u16* y = Y + (size_t)row * DD;
    #pragma unroll
    for (int i = 0; i < 8; i++) {
        const int c = lane + i * 64;
        y[c] = f2bf((v[i] - m) * r * g[c] + b[c]);
    }
}

// ---------------------------------------------------------------------------
__global__ void k_emb(const int* __restrict__ t, float* __restrict__ emb)
{
    const int idx = blockIdx.x * 256 + threadIdx.x;
    if (idx >= BB * DD) return;
    const int b = idx / DD, c = idx % DD;
    const int j = (c < 256) ? c : (c - 256);
    const float freq = expf((float)j * (-9.210340371976184f / 255.0f));
    const float arg = (float)t[b] * freq;
    emb[idx] = (c < 256) ? sinf(arg) : cosf(arg);
}

__global__ __launch_bounds__(256)
void k_wlin(const float* __restrict__ in, int K,
            const float* __restrict__ W, const float* __restrict__ bias,
            float* __restrict__ out, int N, int act)
{
    const int gw   = blockIdx.x * 4 + (threadIdx.x >> 6);
    const int lane = threadIdx.x & 63;
    const int b = gw / N, n = gw % N;
    const float* x = in + (size_t)b * K;
    const float* w = W + (size_t)n * K;
    float s = 0.0f;
    for (int k = lane; k < K; k += 64) s += x[k] * w[k];
    #pragma unroll
    for (int off = 32; off; off >>= 1) s += __shfl_xor(s, off, 64);
    if (lane == 0) {
        s += bias[n];
        if (act == 2) s = s / (1.0f + expf(-s));
        out[gw] = s;
    }
}

// ---------------------------------------------------------------------------

extern "C" void kernel_launch(void* const* d_in, const int* in_sizes, int n_in,
                              void* d_out, int out_size, void* d_ws, size_t ws_size,
                              hipStream_t stream)
{
    const float* x_t   = (const float*)d_in[0];
    const int*   tarr  = (const int*)  d_in[1];
    const float* cond  = (const float*)d_in[2];
    const float* cmask = (const float*)d_in[3];
    const float* sa_qw = (const float*)d_in[4];
    const float* sa_kw = (const float*)d_in[5];
    const float* sa_vw = (const float*)d_in[6];
    const float* sa_ow = (const float*)d_in[7];
    const float* sa_ob = (const float*)d_in[8];
    const float* ca_qw = (const float*)d_in[9];
    const float* ca_kw = (const float*)d_in[10];
    const float* ca_vw = (const float*)d_in[11];
    const float* ca_ow = (const float*)d_in[12];
    const float* ca_ob = (const float*)d_in[13];
    const float* f1w   = (const float*)d_in[14];
    const float* f1b   = (const float*)d_in[15];
    const float* f2w   = (const float*)d_in[16];
    const float* f2b   = (const float*)d_in[17];
    const float* n1g   = (const float*)d_in[18];
    const float* n1b   = (const float*)d_in[19];
    const float* n2g   = (const float*)d_in[20];
    const float* n2b   = (const float*)d_in[21];
    const float* n3g   = (const float*)d_in[22];
    const float* n3b   = (const float*)d_in[23];
    const float* tm1w  = (const float*)d_in[24];
    const float* tm1b  = (const float*)d_in[25];
    const float* tm2w  = (const float*)d_in[26];
    const float* tm2b  = (const float*)d_in[27];
    const float* ttw   = (const float*)d_in[28];
    const float* ttb   = (const float*)d_in[29];
    const float* pinw  = (const float*)d_in[30];
    const float* pinb  = (const float*)d_in[31];
    const float* poutw = (const float*)d_in[32];
    const float* poutb = (const float*)d_in[33];
    const float* fng   = (const float*)d_in[34];
    const float* fnb   = (const float*)d_in[35];

    const int M = BB * LQQ; // 2048
    const size_t MB = 1048576;

    char* w8 = (char*)d_ws;
    float* h   = (float*)(w8);                      // [2048,512] fp32  4 MB
    u16*  xn  = (u16*)(w8 +  4 * MB);               // 2 MB
    u16*  qb  = (u16*)(w8 +  6 * MB);               // 2 MB
    u16*  kb  = (u16*)(w8 +  8 * MB);               // 2 MB (self K)
    u16*  vbT = (u16*)(w8 + 10 * MB);               // [B,H,64,512] 2 MB
    u16*  ubT = (u16*)(w8 + 12 * MB);               // [B,H,64,512] wT 2 MB
    u16*  ob  = (u16*)(w8 + 14 * MB);               // 2 MB
    u16*  a1  = (u16*)(w8 + 16 * MB);               // FFN hidden 8 MB
    u16*  cdb = (u16*)(w8 + 24 * MB);               // cond bf16 512 KB
    u16*  kbc6 = (u16*)(w8 + 25 * MB);              // 6 x [B*LCC, DD] = 3 MB
    u16*  vcT6 = (u16*)(w8 + 28 * MB);              // 6 x [B,H,64,128] = 3 MB
    float* emb = (float*)(w8 + 31 * MB);
    float* h1t = emb + BB * DD;
    float* te  = h1t + BB * DFFN;
    float* ttv = te  + BB * DD;

    const dim3 T256(256);
    const dim3 LN_B(64, 4);
    const long long ZA  = (long long)LQQ * DD;      // 262144
    const long long ZVT = (long long)HH * HD * LQQ; // 262144
    const long long ZWT = (long long)HH * HD * LCC; // 65536
    const long long WST = (long long)DD * DD;       // per-layer weight stride (elems)

    // ---- only remaining conversion: cond tokens (A-operand, reused 12x) ----
    k_cvt<<<(BB * LCC * DD / 4 + 255) / 256, T256, 0, stream>>>(cond, cdb, BB * LCC * DD / 4);

    // ---- time embedding path ----
    k_emb<<<(BB * DD + 255) / 256, 256, 0, stream>>>(tarr, emb);
    k_wlin<<<(BB * DFFN) / 4, T256, 0, stream>>>(emb, DD, tm1w, tm1b, h1t, DFFN, 2);
    k_wlin<<<(BB * DD) / 4,   T256, 0, stream>>>(h1t, DFFN, tm2w, tm2b, te, DD, 0);
    k_wlin<<<(BB * DD) / 4,   T256, 0, stream>>>(te, DD, ttw, ttb, ttv, DD, 0);

    // ---- all-layer cross K: kbc6[L] = cond @ ckw[L]^T  (z = layer, fp32 W) ----
    k_g<32, 64, u16, false, true><<<dim3(DD / 64, (BB * LCC) / 32, NLAYER), T256, 0, stream>>>(
        cdb, 0, 0, DD, ca_kw, nullptr, nullptr, 0, WST, DD,
        kbc6, nullptr, nullptr, 0, (long long)BB * LCC * DD, DD,
        DD, NLAYER, 1.0f, nullptr, nullptr, 0, 0, 0.0f, nullptr, 0, 0, 0, 0, 0, 0, 0);
    // ---- all-layer cross V (transposed): vcT6[L] ----
    k_g<32, 64, u16, false, true><<<dim3(DD / 64, (BB * LCC) / 32, NLAYER), T256, 0, stream>>>(
        cdb, 0, 0, DD, ca_vw, nullptr, nullptr, 0, WST, DD,
        vcT6, nullptr, nullptr, 0, (long long)BB * HH * HD * LCC, DD,
        DD, NLAYER, 1.0f, nullptr, nullptr, 0, 0, 0.0f, nullptr, 0, 0, 0,
        /*wt=*/1, /*shift=*/7, /*sbT=*/ZWT, /*ldct=*/LCC);

    // ---- input projection: h = x_t @ pinw.T + pinb + ttv[b]  (fp32 A and B) ----
    k_g<32, 64, float, false, true, true><<<dim3(DD / 64, M / 32, 1), T256, 0, stream>>>(
        x_t, 0, 0, LATD, pinw, nullptr, nullptr, 0, 0, LATD,
        h, nullptr, nullptr, 0, 0, DD,
        LATD, 1, 1.0f, pinb, ttv, DD, 9, 0.0f, nullptr, 0, 0, 0, 0, 0, 0, 0);

    for (int L = 0; L < NLAYER; L++) {
        const size_t LW = (size_t)L * DD * DD;

        // ======== self-attention with QGFD (P never materialized) ========
        k_ln<<<M / 4, LN_B, 0, stream>>>(h, xn, n1g + (size_t)L * DD, n1b + (size_t)L * DD);

        // fused QKV (z: 0=q, 1=k, 2=v transposed), weights fp32-direct
        k_g<64, 64, u16, true, true><<<dim3(DD / 64, M / 64, 3), T256, 0, stream>>>(
            xn, 0, 0, DD, sa_qw + LW, sa_kw + LW, sa_vw + LW, 0, 0, DD,
            qb, kb, vbT, 0, 0, DD,
            DD, 1, 1.0f, nullptr, nullptr, 0, 0, 0.0f, nullptr, 0, 0, 0,
            /*wt_mask=*/4, /*wt_shift=*/9, /*sbT=*/ZVT, /*ldct=*/LQQ);

        // pass A: S+softmax+u=P@v, wT = (0.5u+0.5v)^T   (no P write)
        k_attn<1><<<dim3(1, LQQ / 64, BB * HH), T256, 0, stream>>>(
            qb, kb, vbT, ubT, nullptr, 0.125f);

        // pass B: recompute S+softmax, ob = P @ wT
        k_attn<2><<<dim3(1, LQQ / 64, BB * HH), T256, 0, stream>>>(
            qb, kb, ubT, ob, nullptr, 0.125f);

        // h += ob @ ow.T + obias
        k_g<32, 64, float, false, true><<<dim3(DD / 64, M / 32, 1), T256, 0, stream>>>(
            ob, 0, 0, DD, sa_ow + LW, nullptr, nullptr, 0, 0, DD,
            h, nullptr, nullptr, 0, 0, DD,
            DD, 1, 1.0f, sa_ob + (size_t)L * DD, h, DD, 0, 0.0f, nullptr, 0, 0, 0, 0, 0, 0, 0);

        // ======== cross-attention ========
        k_ln<<<M / 4, LN_B, 0, stream>>>(h, xn, n2g + (size_t)L * DD, n2b + (size_t)L * DD);

        k_g<32, 64, u16, false, true><<<dim3(DD / 64, M / 32, 1), T256, 0, stream>>>(
            xn, 0, 0, DD, ca_qw + LW, nullptr, nullptr, 0, 0, DD,
            qb, nullptr, nullptr, 0, 0, DD,
            DD, 1, 1.0f, nullptr, nullptr, 0, 0, 0.0f, nullptr, 0, 0, 0, 0, 0, 0, 0);

        // fused Sc+mask+softmax+Pc@vc -> ob
        k_attn<0><<<dim3(1, LQQ / 64, BB * HH), T256, 0, stream>>>(
            qb, kbc6 + (size_t)L * BB * LCC * DD, vcT6 + (size_t)L * BB * HH * HD * LCC,
            ob, cmask, 0.125f);

        // h += ob @ cow.T + cob
        k_g<32, 64, float, false, true><<<dim3(DD / 64, M / 32, 1), T256, 0, stream>>>(
            ob, 0, 0, DD, ca_ow + LW, nullptr, nullptr, 0, 0, DD,
            h, nullptr, nullptr, 0, 0, DD,
            DD, 1, 1.0f, ca_ob + (size_t)L * DD, h, DD, 0, 0.0f, nullptr, 0, 0, 0, 0, 0, 0, 0);

        // ======== FFN ========
        k_ln<<<M / 4, LN_B, 0, stream>>>(h, xn, n3g + (size_t)L * DD, n3b + (size_t)L * DD);

        k_g<64, 64, u16, false, true><<<dim3(DFFN / 64, M / 64, 1), T256, 0, stream>>>(
            xn, 0, 0, DD, f1w + (size_t)L * DFFN * DD, nullptr, nullptr, 0, 0, DD,
            a1, nullptr, nullptr, 0, 0, DFFN,
            DD, 1, 1.0f, f1b + (size_t)L * DFFN, nullptr, 0, 0, 0.0f, nullptr, 0, 0,
            /*act=*/1, 0, 0, 0, 0);
        // w2: 64x64 tile (K=2048 -> halve redundant B-panel traffic vs 32x64)
        k_g<64, 64, float, false, true><<<dim3(DD / 64, M / 64, 1), T256, 0, stream>>>(
            a1, 0, 0, DFFN, f2w + (size_t)L * DD * DFFN, nullptr, nullptr, 0, 0, DFFN,
            h, nullptr, nullptr, 0, 0, DD,
            DFFN, 1, 1.0f, f2b + (size_t)L * DD, h, DD, 0, 0.0f, nullptr, 0, 0, 0, 0, 0, 0, 0);
    }

    // ---- final LN + output projection ----
    k_ln<<<M / 4, LN_B, 0, stream>>>(h, xn, fng, fnb);
    k_g<32, 32, float, false, true><<<dim3(LATD / 32, M / 32, 1), T256, 0, stream>>>(
        xn, 0, 0, DD, poutw, nullptr, nullptr, 0, 0, DD,
        (float*)d_out, nullptr, nullptr, 0, 0, LATD,
        DD, 1, 1.0f, poutb, nullptr, 0, 0, 0.0f, nullptr, 0, 0, 0, 0, 0, 0, 0);
}

// Round 3
// 1677.792 us; speedup vs baseline: 1.1282x; 1.1282x over previous
//
#include <hip/hip_runtime.h>
#include <hip/hip_bf16.h>
#include <type_traits>

#define DD    512
#define HH    8
#define HD    64
#define NLAYER 6
#define DFFN  2048
#define LATD  256
#define BB    4
#define LQQ   512
#define LCC   128

typedef unsigned short u16;
typedef __attribute__((ext_vector_type(8))) short bf16x8;
typedef __attribute__((ext_vector_type(4))) float f32x4;
typedef __attribute__((ext_vector_type(4))) unsigned short u16x4;

__device__ __forceinline__ u16 f2bf(float f) {
    __hip_bfloat16 h = __float2bfloat16(f);
    return __builtin_bit_cast(u16, h);
}
__device__ __forceinline__ float bf2f(u16 u) {
    return __uint_as_float(((unsigned int)u) << 16);
}

// ---------------------------------------------------------------------------
// MFMA bf16 GEMM, all operands bf16, B is [N][K] row-major.
// BK=64, LDS double-buffer + 2-slot register pipeline (round-7, verified).
// MULTI: blockIdx.z selects (B,C) from up to 3; else z=zb*Hdim+zh batches.
// wt: transposed epilogue C[gn*ldct + (gm>>wt_shift)*sbT + (gm&mask)].
// normal: v=alpha*acc + bias[n]; act==1 exact gelu; += res[(gm>>rs)*ldres+gn].
// ---------------------------------------------------------------------------
template<int BM, int BN, typename TC, bool MULTI>
__global__ __launch_bounds__(256)
void k_g(const u16* __restrict__ A, long long sAb, long long sAh, int lda,
         const u16* __restrict__ B1, const u16* __restrict__ B2_, const u16* __restrict__ B3_,
         long long sBb, long long sBh, int ldb,
         TC* __restrict__ C1, TC* __restrict__ C2_, TC* __restrict__ C3_,
         long long sCb, long long sCh, int ldc,
         int K, int Hdim, float alpha,
         const float* __restrict__ bias,
         const float* __restrict__ res, int ldres, int res_shift,
         float beta2, const u16* __restrict__ add2, long long s2b, long long s2h,
         int act, int wt_mask, int wt_shift, long long sbT, int ldct)
{
    constexpr int SK = 72;
    constexpr int FM = BM / 32, FN = BN / 32;
    constexpr int PA = BM / 32, PB = BN / 32;

    const int z = blockIdx.z;
    const u16* Bm;
    TC* C;
    int wt;
    if constexpr (MULTI) {
        Bm = (z == 0) ? B1 : ((z == 1) ? B2_ : B3_);
        C  = (z == 0) ? C1 : ((z == 1) ? C2_ : C3_);
        wt = (wt_mask >> z) & 1;
    } else {
        const int zb = z / Hdim, zh = z % Hdim;
        A += (size_t)(zb * sAb + zh * sAh);
        Bm = B1 + (size_t)(zb * sBb + zh * sBh);
        C  = C1 + (size_t)(zb * sCb + zh * sCh);
        if (add2) add2 += (size_t)(zb * s2b + zh * s2h);
        wt = wt_mask & 1;
    }

    __shared__ u16 Asm[2][BM * SK];
    __shared__ u16 Bsm[2][BN * SK];

    const int t    = threadIdx.x;
    const int wid  = t >> 6, lane = t & 63;
    const int q    = lane >> 4, c = lane & 15;
    const int wm   = (wid >> 1) * (BM / 2), wn = (wid & 1) * (BN / 2);
    const int m0   = blockIdx.y * BM, n0 = blockIdx.x * BN;

    f32x4 acc[FM][FN];
    #pragma unroll
    for (int i = 0; i < FM; i++)
        #pragma unroll
        for (int j = 0; j < FN; j++) acc[i][j] = (f32x4){0.f, 0.f, 0.f, 0.f};

    uint4 ra[2][PA], rb[2][PB];
    const int NI = K >> 6;

    auto loadg = [&](int slot, int kt) {
        #pragma unroll
        for (int p = 0; p < PA; p++) {
            const int idx = p * 256 + t, r = idx >> 3, kg = (idx & 7) << 3;
            ra[slot][p] = *(const uint4*)(A + (size_t)(m0 + r) * lda + kt + kg);
        }
        #pragma unroll
        for (int p = 0; p < PB; p++) {
            const int idx = p * 256 + t, r = idx >> 3, kg = (idx & 7) << 3;
            rb[slot][p] = *(const uint4*)(Bm + (size_t)(n0 + r) * ldb + kt + kg);
        }
    };
    auto store = [&](int buf, int slot) {
        #pragma unroll
        for (int p = 0; p < PA; p++) {
            const int idx = p * 256 + t, r = idx >> 3, kg = (idx & 7) << 3;
            *(uint4*)&Asm[buf][r * SK + kg] = ra[slot][p];
        }
        #pragma unroll
        for (int p = 0; p < PB; p++) {
            const int idx = p * 256 + t, r = idx >> 3, kg = (idx & 7) << 3;
            *(uint4*)&Bsm[buf][r * SK + kg] = rb[slot][p];
        }
    };

    loadg(0, 0);
    if (NI > 1) loadg(1, 64);
    store(0, 0);

    for (int it = 0; it < NI; it++) {
        __syncthreads();
        const int cur = it & 1, nxt = cur ^ 1;
        if (it + 1 < NI) store(nxt, nxt);
        if (it + 2 < NI) loadg(cur, (it + 2) << 6);
        #pragma unroll
        for (int s = 0; s < 2; s++) {
            bf16x8 af[FM], bfv[FN];
            #pragma unroll
            for (int fm = 0; fm < FM; fm++)
                af[fm] = *(const bf16x8*)&Asm[cur][(wm + fm * 16 + c) * SK + s * 32 + q * 8];
            #pragma unroll
            for (int fn = 0; fn < FN; fn++)
                bfv[fn] = *(const bf16x8*)&Bsm[cur][(wn + fn * 16 + c) * SK + s * 32 + q * 8];
            #pragma unroll
            for (int fm = 0; fm < FM; fm++)
                #pragma unroll
                for (int fn = 0; fn < FN; fn++)
                    acc[fm][fn] = __builtin_amdgcn_mfma_f32_16x16x32_bf16(
                        af[fm], bfv[fn], acc[fm][fn], 0, 0, 0);
        }
    }

    if (wt) {
        if constexpr (std::is_same<TC, u16>::value) {
            #pragma unroll
            for (int fm = 0; fm < FM; fm++) {
                const int gm0 = m0 + wm + fm * 16 + q * 4;
                const long long roff =
                    (long long)(gm0 >> wt_shift) * sbT + (gm0 & ((1 << wt_shift) - 1));
                #pragma unroll
                for (int fn = 0; fn < FN; fn++) {
                    const int gn = n0 + wn + fn * 16 + c;
                    const long long a0 = (long long)gn * ldct + roff;
                    u16x4 o;
                    if (add2) {
                        const u16x4 av = *(const u16x4*)&add2[a0];
                        #pragma unroll
                        for (int r = 0; r < 4; r++)
                            o[r] = f2bf(alpha * acc[fm][fn][r] + beta2 * bf2f(av[r]));
                    } else {
                        #pragma unroll
                        for (int r = 0; r < 4; r++)
                            o[r] = f2bf(alpha * acc[fm][fn][r]);
                    }
                    *(u16x4*)&C[a0] = o;
                }
            }
        }
    } else {
        #pragma unroll
        for (int fm = 0; fm < FM; fm++) {
            #pragma unroll
            for (int reg = 0; reg < 4; reg++) {
                const int gm = m0 + wm + fm * 16 + q * 4 + reg;
                #pragma unroll
                for (int fn = 0; fn < FN; fn++) {
                    const int gn = n0 + wn + fn * 16 + c;
                    float v = alpha * acc[fm][fn][reg];
                    if (bias) v += bias[gn];
                    if (act == 1) v = 0.5f * v * (1.0f + erff(v * 0.7071067811865475f));
                    if (res)  v += res[(size_t)(gm >> res_shift) * ldres + gn];
                    if constexpr (std::is_same<TC, u16>::value)
                        C[(size_t)gm * ldc + gn] = f2bf(v);
                    else
                        C[(size_t)gm * ldc + gn] = v;
                }
            }
        }
    }
}

// ---------------------------------------------------------------------------
// 128x128-tile GEMM (m97 structure): global_load_lds width-16 staging,
// XOR-swizzled LDS (linear dest + inverse-swizzled global src + swizzled
// ds_read -> 2-way bank conflicts only). 4 waves (2x2), 64x64 per wave.
// A [M][K] bf16, B [N][K] bf16 row-major, K multiple of 64.
// Epilogue: v = acc + bias[n]; act==1 exact gelu; += res; store TC.
// Use only when grid (N/128)*(M/128) >= ~256 blocks.
// ---------------------------------------------------------------------------
template<typename TC>
__global__ __launch_bounds__(256)
void k_g128(const u16* __restrict__ A, int lda,
            const u16* __restrict__ B, int ldb,
            TC* __restrict__ C, int ldc, int K,
            const float* __restrict__ bias,
            const float* __restrict__ res, int ldres, int act)
{
    __shared__ u16 As[128 * 64];
    __shared__ u16 Bs[128 * 64];

    const int t = threadIdx.x, wid = t >> 6, lane = t & 63;
    const int q = lane >> 4, c = lane & 15;
    const int wr = wid >> 1, wc = wid & 1;
    const int m0 = blockIdx.y * 128, n0 = blockIdx.x * 128;

    // staging decomposition: wave wid, chunk j covers rows wid*32+j*8 .. +8
    const int lr  = lane >> 3;   // row within 8-row chunk
    const int lkb = lane & 7;    // dest 16B-block within row

    f32x4 acc[4][4];
    #pragma unroll
    for (int i = 0; i < 4; i++)
        #pragma unroll
        for (int j = 0; j < 4; j++) acc[i][j] = (f32x4){0.f, 0.f, 0.f, 0.f};

    const int NI = K >> 6;
    for (int it = 0; it < NI; it++) {
        const int kt = it << 6;
        #pragma unroll
        for (int j = 0; j < 4; j++) {
            const int r  = wid * 32 + j * 8 + lr;
            const int kb = lkb ^ (r & 7);          // inverse-swizzled source block
            const u16* ga = A + (size_t)(m0 + r) * lda + kt + kb * 8;
            const u16* gb = B + (size_t)(n0 + r) * ldb + kt + kb * 8;
            u16* la = &As[(wid * 32 + j * 8) * 64];   // wave-uniform LDS base
            u16* lb = &Bs[(wid * 32 + j * 8) * 64];
            __builtin_amdgcn_global_load_lds(
                (const __attribute__((address_space(1))) void*)ga,
                (__attribute__((address_space(3))) void*)la, 16, 0, 0);
            __builtin_amdgcn_global_load_lds(
                (const __attribute__((address_space(1))) void*)gb,
                (__attribute__((address_space(3))) void*)lb, 16, 0, 0);
        }
        __syncthreads();
        #pragma unroll
        for (int s = 0; s < 2; s++) {
            bf16x8 af[4], bfv[4];
            #pragma unroll
            for (int fm = 0; fm < 4; fm++) {
                const int row = wr * 64 + fm * 16 + c;
                const int blk = (s * 4 + q) ^ (row & 7);   // swizzled read
                af[fm] = *(const bf16x8*)&As[row * 64 + blk * 8];
            }
            #pragma unroll
            for (int fn = 0; fn < 4; fn++) {
                const int row = wc * 64 + fn * 16 + c;
                const int blk = (s * 4 + q) ^ (row & 7);
                bfv[fn] = *(const bf16x8*)&Bs[row * 64 + blk * 8];
            }
            #pragma unroll
            for (int fm = 0; fm < 4; fm++)
                #pragma unroll
                for (int fn = 0; fn < 4; fn++)
                    acc[fm][fn] = __builtin_amdgcn_mfma_f32_16x16x32_bf16(
                        af[fm], bfv[fn], acc[fm][fn], 0, 0, 0);
        }
        __syncthreads();
    }

    #pragma unroll
    for (int fm = 0; fm < 4; fm++) {
        #pragma unroll
        for (int reg = 0; reg < 4; reg++) {
            const int gm = m0 + wr * 64 + fm * 16 + q * 4 + reg;
            #pragma unroll
            for (int fn = 0; fn < 4; fn++) {
                const int gn = n0 + wc * 64 + fn * 16 + c;
                float v = acc[fm][fn][reg];
                if (bias) v += bias[gn];
                if (act == 1) v = 0.5f * v * (1.0f + erff(v * 0.7071067811865475f));
                if (res)  v += res[(size_t)gm * ldres + gn];
                if constexpr (std::is_same<TC, u16>::value)
                    C[(size_t)gm * ldc + gn] = f2bf(v);
                else
                    C[(size_t)gm * ldc + gn] = v;
            }
        }
    }
}

// ---------------------------------------------------------------------------
// Fused attention: one block = 64 q-rows x one (b,h) head.
// MODE 0 (cross) : LK=128, key mask, epilogue writes ob rows [B*LQ, DD].
// MODE 1 (self A): LK=512, u = P@v, epilogue wT[b,h,64,512] = (0.5u+0.5v)^T.
// MODE 2 (self B): LK=512, RECOMPUTES S+softmax (bit-identical to MODE 1),
//                  then ob = P @ wT (vT arg = wT buffer), row-major epilogue.
// ---------------------------------------------------------------------------
template<int MODE>
__global__ __launch_bounds__(256)
void k_attn(const u16* __restrict__ qb, const u16* __restrict__ kb,
            const u16* __restrict__ vT, u16* __restrict__ uout,
            const float* __restrict__ mask, float alpha)
{
    constexpr bool CROSS = (MODE == 0);
    constexpr int LK  = CROSS ? LCC : LQQ;
    constexpr int NCT = LK / 128;
    constexpr int NJ  = LK / 16;
    constexpr int SM1 = 64 * 72 * 2 + (CROSS ? 1 : 2) * 128 * 72 * 2;
    constexpr int SM2 = 2 * 64 * 136 * 2;
    constexpr int SMEM = SM1 > SM2 ? SM1 : SM2;
    __shared__ char smem[SMEM];
    u16* Qs = (u16*)smem;
    u16* Ks = (u16*)(smem + 64 * 72 * 2);
    u16* Ps = (u16*)smem;
    u16* Vs = (u16*)(smem + 64 * 136 * 2);

    const int z = blockIdx.z, b = z >> 3, hh = z & 7;
    const int m0 = blockIdx.y * 64;
    const int t = threadIdx.x, w = t >> 6, lane = t & 63;
    const int q = lane >> 4, c = lane & 15;

    const u16* qbase = qb + ((size_t)(b * LQQ + m0)) * DD + hh * HD;
    const u16* kbase = kb + ((size_t)b * LK) * DD + hh * HD;
    const u16* vbase = vT + (size_t)z * HD * LK;

    // ---- stage Q (64 x 64) ----
    #pragma unroll
    for (int p = 0; p < 2; p++) {
        const int idx = p * 256 + t, r = idx >> 3, kg = (idx & 7) << 3;
        *(uint4*)&Qs[r * 72 + kg] = *(const uint4*)(qbase + (size_t)r * DD + kg);
    }

    f32x4 acc[NJ];
    #pragma unroll
    for (int j = 0; j < NJ; j++) acc[j] = (f32x4){0.f, 0.f, 0.f, 0.f};

    auto stageK = [&](u16* dst, int ct) {
        #pragma unroll
        for (int p = 0; p < 4; p++) {
            const int idx = p * 256 + t, r = idx >> 3, kg = (idx & 7) << 3;
            *(uint4*)&dst[r * 72 + kg] =
                *(const uint4*)(kbase + (size_t)(ct * 128 + r) * DD + kg);
        }
    };

    stageK(Ks, 0);
    __syncthreads();
    #pragma unroll
    for (int ct = 0; ct < NCT; ct++) {
        u16* cur = Ks + (!CROSS ? (ct & 1) * (128 * 72) : 0);
        if (!CROSS && ct + 1 < NCT)
            stageK(Ks + ((ct + 1) & 1) * (128 * 72), ct + 1);
        #pragma unroll
        for (int s = 0; s < 2; s++) {
            const bf16x8 af = *(const bf16x8*)&Qs[(w * 16 + c) * 72 + s * 32 + q * 8];
            #pragma unroll
            for (int fn = 0; fn < 8; fn++) {
                const bf16x8 bv = *(const bf16x8*)&cur[(fn * 16 + c) * 72 + s * 32 + q * 8];
                acc[ct * 8 + fn] = __builtin_amdgcn_mfma_f32_16x16x32_bf16(
                    af, bv, acc[ct * 8 + fn], 0, 0, 0);
            }
        }
        if (!CROSS && ct + 1 < NCT) __syncthreads();
    }

    // ---- row softmax (rows q*4+reg per wave; cols j*16+c) ----
    bool msk[NJ];
    #pragma unroll
    for (int j = 0; j < NJ; j++) {
        msk[j] = false;
        if (CROSS && mask) msk[j] = (mask[b * LCC + j * 16 + c] == 0.0f);
    }
    float mx[4] = {-3.402823466e38f, -3.402823466e38f, -3.402823466e38f, -3.402823466e38f};
    #pragma unroll
    for (int j = 0; j < NJ; j++)
        #pragma unroll
        for (int r = 0; r < 4; r++) {
            float x = alpha * acc[j][r];
            if (msk[j]) x = -3.402823466e38f;
            acc[j][r] = x;
            mx[r] = fmaxf(mx[r], x);
        }
    #pragma unroll
    for (int r = 0; r < 4; r++)
        #pragma unroll
        for (int m = 8; m; m >>= 1) mx[r] = fmaxf(mx[r], __shfl_xor(mx[r], m, 64));
    float sum[4] = {0.f, 0.f, 0.f, 0.f};
    #pragma unroll
    for (int j = 0; j < NJ; j++)
        #pragma unroll
        for (int r = 0; r < 4; r++) {
            const float e = expf(acc[j][r] - mx[r]);
            acc[j][r] = e;
            sum[r] += e;
        }
    #pragma unroll
    for (int r = 0; r < 4; r++)
        #pragma unroll
        for (int m = 8; m; m >>= 1) sum[r] += __shfl_xor(sum[r], m, 64);
    #pragma unroll
    for (int r = 0; r < 4; r++) sum[r] = 1.0f / sum[r];
    #pragma unroll
    for (int j = 0; j < NJ; j++)
        #pragma unroll
        for (int r = 0; r < 4; r++) acc[j][r] *= sum[r];

    // ---- phase 2: u = P @ v (MODE 0/1) or ob = P @ wT (MODE 2) ----
    f32x4 ua[4];
    #pragma unroll
    for (int fn = 0; fn < 4; fn++) ua[fn] = (f32x4){0.f, 0.f, 0.f, 0.f};

    __syncthreads();   // phase boundary: Qs/Ks -> Ps/Vs alias
    #pragma unroll
    for (int ct = 0; ct < NCT; ct++) {
        #pragma unroll
        for (int j = 0; j < 8; j++)
            #pragma unroll
            for (int r = 0; r < 4; r++)
                Ps[(w * 16 + q * 4 + r) * 136 + j * 16 + c] = f2bf(acc[ct * 8 + j][r]);
        #pragma unroll
        for (int p = 0; p < 4; p++) {
            const int idx = p * 256 + t, rr = idx >> 4, kg = (idx & 15) << 3;
            *(uint4*)&Vs[rr * 136 + kg] =
                *(const uint4*)(vbase + (size_t)rr * LK + ct * 128 + kg);
        }
        __syncthreads();
        #pragma unroll
        for (int ks = 0; ks < 4; ks++) {
            const bf16x8 af = *(const bf16x8*)&Ps[(w * 16 + c) * 136 + ks * 32 + q * 8];
            #pragma unroll
            for (int fn = 0; fn < 4; fn++) {
                const bf16x8 bv = *(const bf16x8*)&Vs[(fn * 16 + c) * 136 + ks * 32 + q * 8];
                ua[fn] = __builtin_amdgcn_mfma_f32_16x16x32_bf16(af, bv, ua[fn], 0, 0, 0);
            }
        }
        if (ct + 1 < NCT) __syncthreads();
    }

    // ---- epilogue ----
    if (MODE == 1) {
        #pragma unroll
        for (int fn = 0; fn < 4; fn++) {
            const int col = fn * 16 + c;
            const size_t a0 = ((size_t)z * HD + col) * LQQ + m0 + w * 16 + q * 4;
            const u16x4 vv = *(const u16x4*)&vT[a0];
            u16x4 o;
            #pragma unroll
            for (int r = 0; r < 4; r++)
                o[r] = f2bf(0.5f * ua[fn][r] + 0.5f * bf2f(vv[r]));
            *(u16x4*)&uout[a0] = o;
        }
    } else {
        #pragma unroll
        for (int fn = 0; fn < 4; fn++)
            #pragma unroll
            for (int r = 0; r < 4; r++)
                uout[((size_t)b * LQQ + m0 + w * 16 + q * 4 + r) * DD + hh * HD + fn * 16 + c] =
                    f2bf(ua[fn][r]);
    }
}

// ---------------------------------------------------------------------------
#define NSEG 14
struct CvtArgs {
    const float* src[NSEG];
    u16*         dst[NSEG];
    int          beg[NSEG + 1];
    int          n4[NSEG];
};

__global__ __launch_bounds__(256)
void k_cvtm(CvtArgs a)
{
    const int blk = blockIdx.x;
    int s = 0;
    #pragma unroll
    for (int i = 1; i < NSEG; i++) if (blk >= a.beg[i]) s = i;
    const int i4 = (blk - a.beg[s]) * 256 + threadIdx.x;
    if (i4 >= a.n4[s]) return;
    const float4 v = *(const float4*)(a.src[s] + (size_t)i4 * 4);
    u16x4 u = { f2bf(v.x), f2bf(v.y), f2bf(v.z), f2bf(v.w) };
    *(u16x4*)(a.dst[s] + (size_t)i4 * 4) = u;
}

// ---------------------------------------------------------------------------
__global__ __launch_bounds__(256)
void k_ln(const float* __restrict__ X, u16* __restrict__ Y,
          const float* __restrict__ g, const float* __restrict__ b)
{
    const int row  = blockIdx.x * 4 + threadIdx.y;
    const int lane = threadIdx.x;
    const float* x = X + (size_t)row * DD;
    float v[8];
    float s = 0.0f;
    #pragma unroll
    for (int i = 0; i < 8; i++) { v[i] = x[lane + i * 64]; s += v[i]; }
    #pragma unroll
    for (int off = 32; off; off >>= 1) s += __shfl_xor(s, off, 64);
    const float m = s * (1.0f / 512.0f);
    float qq = 0.0f;
    #pragma unroll
    for (int i = 0; i < 8; i++) { const float d = v[i] - m; qq += d * d; }
    #pragma unroll
    for (int off = 32; off; off >>= 1) qq += __shfl_xor(qq, off, 64);
    const float r = rsqrtf(qq * (1.0f / 512.0f) + 1e-5f);
    u16* y = Y + (size_t)row * DD;
    #pragma unroll
    for (int i = 0; i < 8; i++) {
        const int c = lane + i * 64;
        y[c] = f2bf((v[i] - m) * r * g[c] + b[c]);
    }
}

// ---------------------------------------------------------------------------
__global__ void k_emb(const int* __restrict__ t, float* __restrict__ emb)
{
    const int idx = blockIdx.x * 256 + threadIdx.x;
    if (idx >= BB * DD) return;
    const int b = idx / DD, c = idx % DD;
    const int j = (c < 256) ? c : (c - 256);
    const float freq = expf((float)j * (-9.210340371976184f / 255.0f));
    const float arg = (float)t[b] * freq;
    emb[idx] = (c < 256) ? sinf(arg) : cosf(arg);
}

__global__ __launch_bounds__(256)
void k_wlin(const float* __restrict__ in, int K,
            const float* __restrict__ W, const float* __restrict__ bias,
            float* __restrict__ out, int N, int act)
{
    const int gw   = blockIdx.x * 4 + (threadIdx.x >> 6);
    const int lane = threadIdx.x & 63;
    const int b = gw / N, n = gw % N;
    const float* x = in + (size_t)b * K;
    const float* w = W + (size_t)n * K;
    float s = 0.0f;
    for (int k = lane; k < K; k += 64) s += x[k] * w[k];
    #pragma unroll
    for (int off = 32; off; off >>= 1) s += __shfl_xor(s, off, 64);
    if (lane == 0) {
        s += bias[n];
        if (act == 2) s = s / (1.0f + expf(-s));
        out[gw] = s;
    }
}

// ---------------------------------------------------------------------------

extern "C" void kernel_launch(void* const* d_in, const int* in_sizes, int n_in,
                              void* d_out, int out_size, void* d_ws, size_t ws_size,
                              hipStream_t stream)
{
    const float* x_t   = (const float*)d_in[0];
    const int*   tarr  = (const int*)  d_in[1];
    const float* cond  = (const float*)d_in[2];
    const float* cmask = (const float*)d_in[3];
    const float* sa_qw = (const float*)d_in[4];
    const float* sa_kw = (const float*)d_in[5];
    const float* sa_vw = (const float*)d_in[6];
    const float* sa_ow = (const float*)d_in[7];
    const float* sa_ob = (const float*)d_in[8];
    const float* ca_qw = (const float*)d_in[9];
    const float* ca_kw = (const float*)d_in[10];
    const float* ca_vw = (const float*)d_in[11];
    const float* ca_ow = (const float*)d_in[12];
    const float* ca_ob = (const float*)d_in[13];
    const float* f1w   = (const float*)d_in[14];
    const float* f1b   = (const float*)d_in[15];
    const float* f2w   = (const float*)d_in[16];
    const float* f2b   = (const float*)d_in[17];
    const float* n1g   = (const float*)d_in[18];
    const float* n1b   = (const float*)d_in[19];
    const float* n2g   = (const float*)d_in[20];
    const float* n2b   = (const float*)d_in[21];
    const float* n3g   = (const float*)d_in[22];
    const float* n3b   = (const float*)d_in[23];
    const float* tm1w  = (const float*)d_in[24];
    const float* tm1b  = (const float*)d_in[25];
    const float* tm2w  = (const float*)d_in[26];
    const float* tm2b  = (const float*)d_in[27];
    const float* ttw   = (const float*)d_in[28];
    const float* ttb   = (const float*)d_in[29];
    const float* pinw  = (const float*)d_in[30];
    const float* pinb  = (const float*)d_in[31];
    const float* poutw = (const float*)d_in[32];
    const float* poutb = (const float*)d_in[33];
    const float* fng   = (const float*)d_in[34];
    const float* fnb   = (const float*)d_in[35];

    const int M = BB * LQQ; // 2048
    const size_t MB = 1048576;

    char* w8 = (char*)d_ws;
    float* h   = (float*)(w8);                      // [2048,512] fp32  4 MB
    u16*  xn  = (u16*)(w8 +  4 * MB);               // 2 MB
    u16*  qb  = (u16*)(w8 +  6 * MB);               // 2 MB
    u16*  kb  = (u16*)(w8 +  8 * MB);               // 2 MB (self K)
    u16*  vbT = (u16*)(w8 + 10 * MB);               // [B,H,64,512] 2 MB
    u16*  ubT = (u16*)(w8 + 12 * MB);               // [B,H,64,512] wT 2 MB
    u16*  ob  = (u16*)(w8 + 14 * MB);               // 2 MB
    u16*  a1  = (u16*)(w8 + 16 * MB);               // FFN hidden 8 MB
    u16*  xtb = (u16*)(w8 + 16 * MB);               // aliases a1 (dead before FFN)
    u16*  cdb = (u16*)(w8 + 17 * MB);               // aliases a1 (dead before FFN)
    u16*  kbc6 = (u16*)(w8 + 32 * MB);              // 6 x [B*LCC, DD] = 3 MB
    u16*  vcT6 = (u16*)(w8 + 35 * MB);              // 6 x [B,H,64,128] = 3 MB
    float* emb = (float*)(w8 + 38 * MB);
    float* h1t = emb + BB * DD;
    float* te  = h1t + BB * DFFN;
    float* ttv = te  + BB * DD;
    u16* wq  = (u16*)(w8 + 39 * MB);
    u16* wk  = (u16*)(w8 + 42 * MB);
    u16* wv  = (u16*)(w8 + 45 * MB);
    u16* wo  = (u16*)(w8 + 48 * MB);
    u16* cwq = (u16*)(w8 + 51 * MB);
    u16* cwk = (u16*)(w8 + 54 * MB);
    u16* cwv = (u16*)(w8 + 57 * MB);
    u16* cwo = (u16*)(w8 + 60 * MB);
    u16* w1  = (u16*)(w8 + 63 * MB);                // 12 MB
    u16* w2  = (u16*)(w8 + 75 * MB);                // 12 MB
    u16* wpi = (u16*)(w8 + 87 * MB);                // 256 KB
    u16* wpo = (u16*)(w8 + 87 * MB + 262144);       // 256 KB

    const dim3 T256(256);
    const dim3 LN_B(64, 4);
    const long long ZVT = (long long)HH * HD * LQQ; // 262144
    const long long ZWT = (long long)HH * HD * LCC; // 65536

    // ---- one fused bf16 conversion dispatch ----
    {
        const int NW4 = NLAYER * DD * DD / 4;
        const int NF4 = NLAYER * DFFN * DD / 4;
        CvtArgs a;
        const float* srcs[NSEG] = { sa_qw, sa_kw, sa_vw, sa_ow, ca_qw, ca_kw, ca_vw, ca_ow,
                                    f1w, f2w, pinw, poutw, x_t, cond };
        u16* dsts[NSEG] = { wq, wk, wv, wo, cwq, cwk, cwv, cwo,
                            w1, w2, wpi, wpo, xtb, cdb };
        const int n4s[NSEG] = { NW4, NW4, NW4, NW4, NW4, NW4, NW4, NW4,
                                NF4, NF4, DD * LATD / 4, LATD * DD / 4,
                                M * LATD / 4, BB * LCC * DD / 4 };
        int acc = 0;
        for (int i = 0; i < NSEG; i++) {
            a.src[i] = srcs[i]; a.dst[i] = dsts[i]; a.n4[i] = n4s[i];
            a.beg[i] = acc; acc += (n4s[i] + 255) / 256;
        }
        a.beg[NSEG] = acc;
        k_cvtm<<<acc, T256, 0, stream>>>(a);
    }

    // ---- time embedding path ----
    k_emb<<<(BB * DD + 255) / 256, 256, 0, stream>>>(tarr, emb);
    k_wlin<<<(BB * DFFN) / 4, T256, 0, stream>>>(emb, DD, tm1w, tm1b, h1t, DFFN, 2);
    k_wlin<<<(BB * DD) / 4,   T256, 0, stream>>>(h1t, DFFN, tm2w, tm2b, te, DD, 0);
    k_wlin<<<(BB * DD) / 4,   T256, 0, stream>>>(te, DD, ttw, ttb, ttv, DD, 0);

    // ---- all-layer cross K: kbc6[L] = cond @ ckw[L]^T  (z = layer) ----
    k_g<32, 64, u16, false><<<dim3(DD / 64, (BB * LCC) / 32, NLAYER), T256, 0, stream>>>(
        cdb, 0, 0, DD, cwk, nullptr, nullptr, 0, (long long)DD * DD, DD,
        kbc6, nullptr, nullptr, 0, (long long)BB * LCC * DD, DD,
        DD, NLAYER, 1.0f, nullptr, nullptr, 0, 0, 0.0f, nullptr, 0, 0, 0, 0, 0, 0, 0);
    // ---- all-layer cross V (transposed): vcT6[L] ----
    k_g<32, 64, u16, false><<<dim3(DD / 64, (BB * LCC) / 32, NLAYER), T256, 0, stream>>>(
        cdb, 0, 0, DD, cwv, nullptr, nullptr, 0, (long long)DD * DD, DD,
        vcT6, nullptr, nullptr, 0, (long long)BB * HH * HD * LCC, DD,
        DD, NLAYER, 1.0f, nullptr, nullptr, 0, 0, 0.0f, nullptr, 0, 0, 0,
        /*wt=*/1, /*shift=*/7, /*sbT=*/ZWT, /*ldct=*/LCC);

    // ---- input projection: h = x_t @ pinw.T + pinb + ttv[b] ----
    k_g<32, 64, float, false><<<dim3(DD / 64, M / 32, 1), T256, 0, stream>>>(
        xtb, 0, 0, LATD, wpi, nullptr, nullptr, 0, 0, LATD,
        h, nullptr, nullptr, 0, 0, DD,
        LATD, 1, 1.0f, pinb, ttv, DD, 9, 0.0f, nullptr, 0, 0, 0, 0, 0, 0, 0);

    for (int L = 0; L < NLAYER; L++) {
        const size_t LW = (size_t)L * DD * DD;

        // ======== self-attention with QGFD (P never materialized) ========
        k_ln<<<M / 4, LN_B, 0, stream>>>(h, xn, n1g + (size_t)L * DD, n1b + (size_t)L * DD);

        // fused QKV (z: 0=q, 1=k, 2=v transposed)
        k_g<64, 64, u16, true><<<dim3(DD / 64, M / 64, 3), T256, 0, stream>>>(
            xn, 0, 0, DD, wq + LW, wk + LW, wv + LW, 0, 0, DD,
            qb, kb, vbT, 0, 0, DD,
            DD, 1, 1.0f, nullptr, nullptr, 0, 0, 0.0f, nullptr, 0, 0, 0,
            /*wt_mask=*/4, /*wt_shift=*/9, /*sbT=*/ZVT, /*ldct=*/LQQ);

        // pass A: S+softmax+u=P@v, wT = (0.5u+0.5v)^T   (no P write)
        k_attn<1><<<dim3(1, LQQ / 64, BB * HH), T256, 0, stream>>>(
            qb, kb, vbT, ubT, nullptr, 0.125f);

        // pass B: recompute S+softmax, ob = P @ wT
        k_attn<2><<<dim3(1, LQQ / 64, BB * HH), T256, 0, stream>>>(
            qb, kb, ubT, ob, nullptr, 0.125f);

        // h += ob @ ow.T + obias
        k_g<32, 64, float, false><<<dim3(DD / 64, M / 32, 1), T256, 0, stream>>>(
            ob, 0, 0, DD, wo + LW, nullptr, nullptr, 0, 0, DD,
            h, nullptr, nullptr, 0, 0, DD,
            DD, 1, 1.0f, sa_ob + (size_t)L * DD, h, DD, 0, 0.0f, nullptr, 0, 0, 0, 0, 0, 0, 0);

        // ======== cross-attention ========
        k_ln<<<M / 4, LN_B, 0, stream>>>(h, xn, n2g + (size_t)L * DD, n2b + (size_t)L * DD);

        k_g<32, 64, u16, false><<<dim3(DD / 64, M / 32, 1), T256, 0, stream>>>(
            xn, 0, 0, DD, cwq + LW, nullptr, nullptr, 0, 0, DD,
            qb, nullptr, nullptr, 0, 0, DD,
            DD, 1, 1.0f, nullptr, nullptr, 0, 0, 0.0f, nullptr, 0, 0, 0, 0, 0, 0, 0);

        // fused Sc+mask+softmax+Pc@vc -> ob
        k_attn<0><<<dim3(1, LQQ / 64, BB * HH), T256, 0, stream>>>(
            qb, kbc6 + (size_t)L * BB * LCC * DD, vcT6 + (size_t)L * BB * HH * HD * LCC,
            ob, cmask, 0.125f);

        // h += ob @ cow.T + cob
        k_g<32, 64, float, false><<<dim3(DD / 64, M / 32, 1), T256, 0, stream>>>(
            ob, 0, 0, DD, cwo + LW, nullptr, nullptr, 0, 0, DD,
            h, nullptr, nullptr, 0, 0, DD,
            DD, 1, 1.0f, ca_ob + (size_t)L * DD, h, DD, 0, 0.0f, nullptr, 0, 0, 0, 0, 0, 0, 0);

        // ======== FFN ========
        k_ln<<<M / 4, LN_B, 0, stream>>>(h, xn, n3g + (size_t)L * DD, n3b + (size_t)L * DD);

        // w1: 128x128 m97-structure kernel (grid 16x16 = 256 blocks = 1/CU)
        k_g128<u16><<<dim3(DFFN / 128, M / 128, 1), T256, 0, stream>>>(
            xn, DD, w1 + (size_t)L * DFFN * DD, DD,
            a1, DFFN, DD, f1b + (size_t)L * DFFN, nullptr, 0, /*act=*/1);

        k_g<32, 64, float, false><<<dim3(DD / 64, M / 32, 1), T256, 0, stream>>>(
            a1, 0, 0, DFFN, w2 + (size_t)L * DD * DFFN, nullptr, nullptr, 0, 0, DFFN,
            h, nullptr, nullptr, 0, 0, DD,
            DFFN, 1, 1.0f, f2b + (size_t)L * DD, h, DD, 0, 0.0f, nullptr, 0, 0, 0, 0, 0, 0, 0);
    }

    // ---- final LN + output projection ----
    k_ln<<<M / 4, LN_B, 0, stream>>>(h, xn, fng, fnb);
    k_g<32, 32, float, false><<<dim3(LATD / 32, M / 32, 1), T256, 0, stream>>>(
        xn, 0, 0, DD, wpo, nullptr, nullptr, 0, 0, DD,
        (float*)d_out, nullptr, nullptr, 0, 0, LATD,
        DD, 1, 1.0f, poutb, nullptr, 0, 0, 0.0f, nullptr, 0, 0, 0, 0, 0, 0, 0);
}